// Round 6
// baseline (256.427 us; speedup 1.0000x reference)
//
#include <hip/hip_runtime.h>
#include <math.h>

#define N_NODES 40000
#define N_EDGES 640000
#define DIM     128
#define N_GRAPHS 64
#define N_CLS   100
#define N_LAYERS 3
#define EPSN    1e-12f

// ---------------- CSR build ----------------

__global__ void k_zero_int(int* __restrict__ a, int n) {
    int i = blockIdx.x * blockDim.x + threadIdx.x;
    if (i < n) a[i] = 0;
}

__global__ void k_count(const int* __restrict__ dst, int* __restrict__ counts) {
    int e = blockIdx.x * blockDim.x + threadIdx.x;
    if (e < N_EDGES) atomicAdd(&counts[dst[e]], 1);
}

#define SCAN_T 1024
#define SCAN_V 40   // SCAN_T * SCAN_V >= N_NODES ; N_NODES/SCAN_V = 1000 exact
__global__ void k_scan(const int* __restrict__ counts, int* __restrict__ offsets) {
    __shared__ int lds[SCAN_T];
    int t = threadIdx.x;
    int base = t * SCAN_V;
    int tsum = 0;
    if (base < N_NODES) {
        for (int k = 0; k < SCAN_V; ++k) tsum += counts[base + k];
    }
    lds[t] = tsum; __syncthreads();
    int x = tsum;
    for (int off = 1; off < SCAN_T; off <<= 1) {
        int y = (t >= off) ? lds[t - off] : 0;
        __syncthreads();
        x += y;
        lds[t] = x;
        __syncthreads();
    }
    int excl = x - tsum;
    if (base < N_NODES) {
        int run = excl;
        for (int k = 0; k < SCAN_V; ++k) {
            offsets[base + k] = run;
            run += counts[base + k];
        }
    }
    if (t == (N_NODES / SCAN_V)) offsets[N_NODES] = excl;  // total = E
}

__global__ void k_scatter(const int* __restrict__ src, const int* __restrict__ dst,
                          const int* __restrict__ offsets, int* __restrict__ cursor,
                          int* __restrict__ csr_src) {
    int e = blockIdx.x * blockDim.x + threadIdx.x;
    if (e >= N_EDGES) return;
    int d = dst[e];
    int p = offsets[d] + atomicAdd(&cursor[d], 1);
    csr_src[p] = src[e];
}

// ---------------- per-layer kernels ----------------

// one wave per node: inv[v] = 1/(||h_v|| + eps)  (layer-0 input only)
__global__ void k_norm(const float* __restrict__ h, float* __restrict__ inv) {
    int node = (blockIdx.x * blockDim.x + threadIdx.x) >> 6;
    int lane = threadIdx.x & 63;
    if (node >= N_NODES) return;
    const float* row = h + (size_t)node * DIM;
    float x0 = row[lane], x1 = row[lane + 64];
    float ss = x0 * x0 + x1 * x1;
    #pragma unroll
    for (int o = 32; o; o >>= 1) ss += __shfl_xor(ss, o);
    if (lane == 0) inv[node] = 1.0f / (sqrtf(ss) + EPSN);
}

// Fused edge-score + segment-softmax + aggregate.
// One wave per node; wave = 4 groups of 16 lanes; each group owns 2 edges per
// batch of 8. Software-pipelined: next batch's rows are prefetched while the
// current batch computes. Scores = beta * cosine in [-1,1] -> exp bounded,
// no max-subtraction needed (softmax shift-invariance).
__device__ __forceinline__ float dot8(float4 a0, float4 a1, float4 b0, float4 b1) {
    return a0.x * b0.x + a0.y * b0.y + a0.z * b0.z + a0.w * b0.w
         + a1.x * b1.x + a1.y * b1.y + a1.z * b1.z + a1.w * b1.w;
}

__global__ __launch_bounds__(256, 4)
void k_fused(const float* __restrict__ h,
             const float* __restrict__ inv_in,
             const int* __restrict__ csr_src,
             const int* __restrict__ offsets,
             const float* __restrict__ betas, int layer,
             float* __restrict__ h_out,
             float* __restrict__ inv_out) {
    int node = (blockIdx.x * blockDim.x + threadIdx.x) >> 6;
    int lane = threadIdx.x & 63;
    if (node >= N_NODES) return;
    int grp = lane >> 4;   // 0..3
    int t   = lane & 15;   // feature sublane

    int off = offsets[node];
    int deg = offsets[node + 1] - off;

    const float4* h4 = (const float4*)h;
    size_t nrow = (size_t)node * 32;
    float4 hda = h4[nrow + t];
    float4 hdb = h4[nrow + 16 + t];
    float bi = betas[layer] * inv_in[node];

    float dsum = 0.f;
    float4 accA = make_float4(0.f, 0.f, 0.f, 0.f);
    float4 accB = make_float4(0.f, 0.f, 0.f, 0.f);

    if (deg > 0) {
        int nb = (deg + 7) >> 3;      // batches of 8 edges (2 per group)
        int last = deg - 1;
        // ---- prefetch batch 0 ----
        int j0 = grp;     if (j0 > last) j0 = last;
        int j1 = 4 + grp; if (j1 > last) j1 = last;
        int cs0 = csr_src[off + j0], cs1 = csr_src[off + j1];
        size_t cr0 = (size_t)cs0 * 32, cr1 = (size_t)cs1 * 32;
        float4 c0a = h4[cr0 + t], c0b = h4[cr0 + 16 + t];
        float4 c1a = h4[cr1 + t], c1b = h4[cr1 + 16 + t];
        float civ0 = inv_in[cs0], civ1 = inv_in[cs1];

        for (int b = 0; b < nb; ++b) {
            int base = b << 3;
            bool v0 = (base + grp)     <= last;
            bool v1 = (base + 4 + grp) <= last;

            // ---- prefetch next batch (wave-uniform branch) ----
            float4 n0a = c0a, n0b = c0b, n1a = c1a, n1b = c1b;
            float niv0 = civ0, niv1 = civ1;
            if (b + 1 < nb) {
                int k0 = base + 8 + grp;  if (k0 > last) k0 = last;
                int k1 = base + 12 + grp; if (k1 > last) k1 = last;
                int ns0 = csr_src[off + k0], ns1 = csr_src[off + k1];
                size_t nr0 = (size_t)ns0 * 32, nr1 = (size_t)ns1 * 32;
                n0a = h4[nr0 + t]; n0b = h4[nr0 + 16 + t];
                n1a = h4[nr1 + t]; n1b = h4[nr1 + 16 + t];
                niv0 = inv_in[ns0]; niv1 = inv_in[ns1];
            }

            // ---- compute current batch ----
            float p0 = dot8(c0a, c0b, hda, hdb);
            float p1 = dot8(c1a, c1b, hda, hdb);
            #pragma unroll
            for (int o = 8; o; o >>= 1) {
                p0 += __shfl_xor(p0, o);
                p1 += __shfl_xor(p1, o);
            }
            float w0 = v0 ? __expf(bi * civ0 * p0) : 0.f;
            float w1 = v1 ? __expf(bi * civ1 * p1) : 0.f;
            dsum += w0 + w1;
            accA.x += w0 * c0a.x + w1 * c1a.x;
            accA.y += w0 * c0a.y + w1 * c1a.y;
            accA.z += w0 * c0a.z + w1 * c1a.z;
            accA.w += w0 * c0a.w + w1 * c1a.w;
            accB.x += w0 * c0b.x + w1 * c1b.x;
            accB.y += w0 * c0b.y + w1 * c1b.y;
            accB.z += w0 * c0b.z + w1 * c1b.z;
            accB.w += w0 * c0b.w + w1 * c1b.w;

            // ---- rotate ----
            c0a = n0a; c0b = n0b; c1a = n1a; c1b = n1b;
            civ0 = niv0; civ1 = niv1;
        }

        // merge the 4 group partials (plain sums)
        #pragma unroll
        for (int o = 16; o < 64; o <<= 1) {
            dsum   += __shfl_xor(dsum, o);
            accA.x += __shfl_xor(accA.x, o);
            accA.y += __shfl_xor(accA.y, o);
            accA.z += __shfl_xor(accA.z, o);
            accA.w += __shfl_xor(accA.w, o);
            accB.x += __shfl_xor(accB.x, o);
            accB.y += __shfl_xor(accB.y, o);
            accB.z += __shfl_xor(accB.z, o);
            accB.w += __shfl_xor(accB.w, o);
        }
        float invd = 1.0f / dsum;
        accA.x *= invd; accA.y *= invd; accA.z *= invd; accA.w *= invd;
        accB.x *= invd; accB.y *= invd; accB.z *= invd; accB.w *= invd;
    }

    if (grp == 0) {
        float4* o4 = (float4*)h_out + nrow;
        o4[t]      = accA;
        o4[16 + t] = accB;
    }

    // fused inv-norm of the output row (for next layer's scores)
    float ss = accA.x * accA.x + accA.y * accA.y + accA.z * accA.z + accA.w * accA.w
             + accB.x * accB.x + accB.y * accB.y + accB.z * accB.z + accB.w * accB.w;
    #pragma unroll
    for (int o = 8; o; o >>= 1) ss += __shfl_xor(ss, o);
    if (lane == 0) inv_out[node] = 1.0f / (sqrtf(ss) + EPSN);
}

// ---------------- readout ----------------

#define POOL_BLOCKS 640
__global__ void k_pool_partial(const float* __restrict__ h, const int* __restrict__ gid,
                               float* __restrict__ hgsum, int* __restrict__ gcount) {
    int nPer = (N_NODES + gridDim.x - 1) / gridDim.x;
    int n0 = blockIdx.x * nPer;
    int n1 = n0 + nPer; if (n1 > N_NODES) n1 = N_NODES;
    if (n0 >= n1) return;
    int c = threadIdx.x;  // 0..127 column
    int curg = gid[n0];
    int segstart = n0;
    float acc = 0.f;
    for (int n = n0; n < n1; ++n) {
        int g = gid[n];
        if (g != curg) {
            atomicAdd(&hgsum[curg * DIM + c], acc);
            if (c == 0) atomicAdd(&gcount[curg], n - segstart);
            acc = 0.f; curg = g; segstart = n;
        }
        acc += h[(size_t)n * DIM + c];
    }
    atomicAdd(&hgsum[curg * DIM + c], acc);
    if (c == 0) atomicAdd(&gcount[curg], n1 - segstart);
}

__global__ void k_cls(const float* __restrict__ hgsum, const int* __restrict__ gcount,
                      const float* __restrict__ W, const float* __restrict__ b,
                      float* __restrict__ out) {
    int g = blockIdx.x;
    int c = threadIdx.x;
    if (c >= N_CLS) return;
    float invc = 1.0f / fmaxf((float)gcount[g], 1.0f);
    float acc = 0.f;
    #pragma unroll 8
    for (int d = 0; d < DIM; ++d) acc += hgsum[g * DIM + d] * W[d * N_CLS + c];
    out[g * N_CLS + c] = b[c] + acc * invc;
}

// ---------------- launch ----------------

extern "C" void kernel_launch(void* const* d_in, const int* in_sizes, int n_in,
                              void* d_out, int out_size, void* d_ws, size_t ws_size,
                              hipStream_t stream) {
    const float* h_in  = (const float*)d_in[0];
    const int*   src   = (const int*)  d_in[1];
    const int*   dst   = (const int*)  d_in[2];
    const int*   gid   = (const int*)  d_in[3];
    const float* betas = (const float*)d_in[4];
    const float* W     = (const float*)d_in[5];
    const float* bcls  = (const float*)d_in[6];
    float* out = (float*)d_out;

    char* p = (char*)d_ws;
    float* h0      = (float*)p; p += (size_t)N_NODES * DIM * 4;   // 20.48 MB
    float* h1      = (float*)p; p += (size_t)N_NODES * DIM * 4;   // 20.48 MB
    float* inv0    = (float*)p; p += (size_t)N_NODES * 4;
    float* inv1    = (float*)p; p += (size_t)N_NODES * 4;
    // --- contiguous zero-init region ---
    int*   counts  = (int*)p;   p += (size_t)N_NODES * 4;
    int*   cursor  = (int*)p;   p += (size_t)N_NODES * 4;
    float* hgsum   = (float*)p; p += (size_t)N_GRAPHS * DIM * 4;
    int*   gcount  = (int*)p;   p += (size_t)N_GRAPHS * 4;
    // -----------------------------------
    int*   offsets = (int*)p;   p += (size_t)(N_NODES + 4) * 4;   // N+1 used, padded
    int*   csr_src = (int*)p;   p += (size_t)N_EDGES * 4;

    const int ZERO_N = 2 * N_NODES + N_GRAPHS * DIM + N_GRAPHS;

    // ---- CSR build (src/dst constant across layers) ----
    k_zero_int<<<(ZERO_N + 255) / 256, 256, 0, stream>>>(counts, ZERO_N);
    k_count<<<(N_EDGES + 255) / 256, 256, 0, stream>>>(dst, counts);
    k_scan<<<1, SCAN_T, 0, stream>>>(counts, offsets);
    k_scatter<<<(N_EDGES + 255) / 256, 256, 0, stream>>>(src, dst, offsets, cursor, csr_src);

    // ---- 3 AGNN layers (fused; h AND inv double-buffered) ----
    const float* cur = h_in;
    float* hbufs[2]   = { h0, h1 };
    float* invbufs[2] = { inv0, inv1 };
    k_norm<<<N_NODES / 4, 256, 0, stream>>>(cur, invbufs[0]);   // layer-0 input norm
    for (int l = 0; l < N_LAYERS; ++l) {
        float* nxt = hbufs[l & 1];
        k_fused<<<N_NODES / 4, 256, 0, stream>>>(cur, invbufs[l & 1],
                                                 csr_src, offsets, betas, l,
                                                 nxt, invbufs[(l + 1) & 1]);
        cur = nxt;
    }

    // ---- readout ----
    k_pool_partial<<<POOL_BLOCKS, DIM, 0, stream>>>(cur, gid, hgsum, gcount);
    k_cls<<<N_GRAPHS, DIM, 0, stream>>>(hgsum, gcount, W, bcls, out);
}

// Round 7
// 213.339 us; speedup vs baseline: 1.2020x; 1.2020x over previous
//
#include <hip/hip_runtime.h>
#include <hip/hip_fp16.h>
#include <math.h>

#define N_NODES 40000
#define N_EDGES 640000
#define DIM     128
#define N_GRAPHS 64
#define N_CLS   100
#define N_LAYERS 3
#define EPSN    1e-12f

// ---------------- CSR build ----------------

__global__ void k_zero_int(int* __restrict__ a, int n) {
    int i = blockIdx.x * blockDim.x + threadIdx.x;
    if (i < n) a[i] = 0;
}

__global__ void k_count(const int* __restrict__ dst, int* __restrict__ counts) {
    int e = blockIdx.x * blockDim.x + threadIdx.x;
    if (e < N_EDGES) atomicAdd(&counts[dst[e]], 1);
}

#define SCAN_T 1024
#define SCAN_V 40   // SCAN_T * SCAN_V >= N_NODES ; N_NODES/SCAN_V = 1000 exact
__global__ void k_scan(const int* __restrict__ counts, int* __restrict__ offsets) {
    __shared__ int lds[SCAN_T];
    int t = threadIdx.x;
    int base = t * SCAN_V;
    int tsum = 0;
    if (base < N_NODES) {
        for (int k = 0; k < SCAN_V; ++k) tsum += counts[base + k];
    }
    lds[t] = tsum; __syncthreads();
    int x = tsum;
    for (int off = 1; off < SCAN_T; off <<= 1) {
        int y = (t >= off) ? lds[t - off] : 0;
        __syncthreads();
        x += y;
        lds[t] = x;
        __syncthreads();
    }
    int excl = x - tsum;
    if (base < N_NODES) {
        int run = excl;
        for (int k = 0; k < SCAN_V; ++k) {
            offsets[base + k] = run;
            run += counts[base + k];
        }
    }
    if (t == (N_NODES / SCAN_V)) offsets[N_NODES] = excl;  // total = E
}

__global__ void k_scatter(const int* __restrict__ src, const int* __restrict__ dst,
                          const int* __restrict__ offsets, int* __restrict__ cursor,
                          int* __restrict__ csr_src) {
    int e = blockIdx.x * blockDim.x + threadIdx.x;
    if (e >= N_EDGES) return;
    int d = dst[e];
    int p = offsets[d] + atomicAdd(&cursor[d], 1);
    csr_src[p] = src[e];
}

// ---------------- per-layer kernels ----------------

// one wave per node: inv[v] = 1/(||h_v||+eps) AND pack the f32 input row into
// the fp16 gather table. Lane l owns elements [2l, 2l+1].
__global__ void k_norm(const float* __restrict__ h, float* __restrict__ inv,
                       __half2* __restrict__ hh) {
    int node = (blockIdx.x * blockDim.x + threadIdx.x) >> 6;
    int lane = threadIdx.x & 63;
    if (node >= N_NODES) return;
    const float2* r2 = (const float2*)(h + (size_t)node * DIM);
    float2 v = r2[lane];
    float ss = v.x * v.x + v.y * v.y;
    #pragma unroll
    for (int o = 32; o; o >>= 1) ss += __shfl_xor(ss, o);
    if (lane == 0) inv[node] = 1.0f / (sqrtf(ss) + EPSN);
    hh[(size_t)node * 64 + lane] = __floats2half2_rn(v.x, v.y);
}

// Fused edge-score + segment-softmax + aggregate on the fp16 table.
// One wave per node; 4 groups of 16 lanes; each group owns 2 edges per batch
// of 8. Lane t owns features [8t..8t+7] = one int4 (8 halves) per row.
// All math in f32 (fp16 is storage only). Scores = beta*cosine in [-1,1], so
// exp is bounded: no max-subtraction needed (softmax shift-invariance).
union H8 { int4 i4; __half2 h2[4]; };

__device__ __forceinline__ void cvt8(const H8& u, float* f) {
    #pragma unroll
    for (int k = 0; k < 4; ++k) {
        float2 v = __half22float2(u.h2[k]);
        f[2 * k]     = v.x;
        f[2 * k + 1] = v.y;
    }
}

template <bool LAST>
__global__ void k_fused(const int4* __restrict__ hh_in,      // fp16 table, 16 int4/row
                        const float* __restrict__ inv_in,
                        const int* __restrict__ csr_src,
                        const int* __restrict__ offsets,
                        const float* __restrict__ betas, int layer,
                        int4* __restrict__ hh_out,            // fp16 table (if !LAST)
                        float* __restrict__ h_out_f32,        // f32 rows (if LAST)
                        float* __restrict__ inv_out) {
    int node = (blockIdx.x * blockDim.x + threadIdx.x) >> 6;
    int lane = threadIdx.x & 63;
    if (node >= N_NODES) return;
    int grp = lane >> 4;   // 0..3
    int t   = lane & 15;   // feature sublane: owns features [8t..8t+7]

    int off = offsets[node];
    int deg = offsets[node + 1] - off;

    size_t nrow16 = (size_t)node * 16;
    H8 selfu; selfu.i4 = hh_in[nrow16 + t];
    float hd[8]; cvt8(selfu, hd);
    float bi = betas[layer] * inv_in[node];

    float dsum = 0.f;
    float ac[8];
    #pragma unroll
    for (int k = 0; k < 8; ++k) ac[k] = 0.f;

    if (deg > 0) {
        int last = deg - 1;
        int jb = 0;
        // full batches: 8 edges (2 per group), no bounds checks
        for (; jb + 8 <= deg; jb += 8) {
            int s0 = csr_src[off + jb + grp];
            int s1 = csr_src[off + jb + 4 + grp];
            H8 u0, u1;
            u0.i4 = hh_in[(size_t)s0 * 16 + t];
            u1.i4 = hh_in[(size_t)s1 * 16 + t];
            float iv0 = inv_in[s0], iv1 = inv_in[s1];
            float f0[8], f1[8];
            cvt8(u0, f0); cvt8(u1, f1);
            float p0 = 0.f, p1 = 0.f;
            #pragma unroll
            for (int k = 0; k < 8; ++k) { p0 += f0[k] * hd[k]; p1 += f1[k] * hd[k]; }
            #pragma unroll
            for (int o = 8; o; o >>= 1) {
                p0 += __shfl_xor(p0, o);
                p1 += __shfl_xor(p1, o);
            }
            float w0 = __expf(bi * iv0 * p0);
            float w1 = __expf(bi * iv1 * p1);
            dsum += w0 + w1;
            #pragma unroll
            for (int k = 0; k < 8; ++k) ac[k] += w0 * f0[k] + w1 * f1[k];
        }
        // clamped tail: passes of 4 edges (1 per group), invalid -> w=0
        for (; jb < deg; jb += 4) {
            int j = jb + grp;
            bool valid = j <= last;
            int idx = valid ? j : last;
            int s = csr_src[off + idx];
            H8 u; u.i4 = hh_in[(size_t)s * 16 + t];
            float iv = inv_in[s];
            float f[8]; cvt8(u, f);
            float p = 0.f;
            #pragma unroll
            for (int k = 0; k < 8; ++k) p += f[k] * hd[k];
            #pragma unroll
            for (int o = 8; o; o >>= 1) p += __shfl_xor(p, o);
            float w = valid ? __expf(bi * iv * p) : 0.f;
            dsum += w;
            #pragma unroll
            for (int k = 0; k < 8; ++k) ac[k] += w * f[k];
        }

        // merge the 4 group partials (plain sums)
        #pragma unroll
        for (int o = 16; o < 64; o <<= 1) {
            dsum += __shfl_xor(dsum, o);
            #pragma unroll
            for (int k = 0; k < 8; ++k) ac[k] += __shfl_xor(ac[k], o);
        }
        float invd = 1.0f / dsum;
        #pragma unroll
        for (int k = 0; k < 8; ++k) ac[k] *= invd;
    }

    if (LAST) {
        if (grp == 0) {
            float4* o4 = (float4*)(h_out_f32 + (size_t)node * DIM);
            o4[2 * t]     = make_float4(ac[0], ac[1], ac[2], ac[3]);
            o4[2 * t + 1] = make_float4(ac[4], ac[5], ac[6], ac[7]);
        }
    } else {
        if (grp == 0) {
            H8 w;
            #pragma unroll
            for (int k = 0; k < 4; ++k)
                w.h2[k] = __floats2half2_rn(ac[2 * k], ac[2 * k + 1]);
            hh_out[nrow16 + t] = w.i4;
        }
        // fused inv-norm of the output row (for next layer's scores)
        float ss = 0.f;
        #pragma unroll
        for (int k = 0; k < 8; ++k) ss += ac[k] * ac[k];
        #pragma unroll
        for (int o = 8; o; o >>= 1) ss += __shfl_xor(ss, o);
        if (lane == 0) inv_out[node] = 1.0f / (sqrtf(ss) + EPSN);
    }
}

// ---------------- readout ----------------

#define POOL_BLOCKS 640
__global__ void k_pool_partial(const float* __restrict__ h, const int* __restrict__ gid,
                               float* __restrict__ hgsum, int* __restrict__ gcount) {
    int nPer = (N_NODES + gridDim.x - 1) / gridDim.x;
    int n0 = blockIdx.x * nPer;
    int n1 = n0 + nPer; if (n1 > N_NODES) n1 = N_NODES;
    if (n0 >= n1) return;
    int c = threadIdx.x;  // 0..127 column
    int curg = gid[n0];
    int segstart = n0;
    float acc = 0.f;
    for (int n = n0; n < n1; ++n) {
        int g = gid[n];
        if (g != curg) {
            atomicAdd(&hgsum[curg * DIM + c], acc);
            if (c == 0) atomicAdd(&gcount[curg], n - segstart);
            acc = 0.f; curg = g; segstart = n;
        }
        acc += h[(size_t)n * DIM + c];
    }
    atomicAdd(&hgsum[curg * DIM + c], acc);
    if (c == 0) atomicAdd(&gcount[curg], n1 - segstart);
}

__global__ void k_cls(const float* __restrict__ hgsum, const int* __restrict__ gcount,
                      const float* __restrict__ W, const float* __restrict__ b,
                      float* __restrict__ out) {
    int g = blockIdx.x;
    int c = threadIdx.x;
    if (c >= N_CLS) return;
    float invc = 1.0f / fmaxf((float)gcount[g], 1.0f);
    float acc = 0.f;
    #pragma unroll 8
    for (int d = 0; d < DIM; ++d) acc += hgsum[g * DIM + d] * W[d * N_CLS + c];
    out[g * N_CLS + c] = b[c] + acc * invc;
}

// ---------------- launch ----------------

extern "C" void kernel_launch(void* const* d_in, const int* in_sizes, int n_in,
                              void* d_out, int out_size, void* d_ws, size_t ws_size,
                              hipStream_t stream) {
    const float* h_in  = (const float*)d_in[0];
    const int*   src   = (const int*)  d_in[1];
    const int*   dst   = (const int*)  d_in[2];
    const int*   gid   = (const int*)  d_in[3];
    const float* betas = (const float*)d_in[4];
    const float* W     = (const float*)d_in[5];
    const float* bcls  = (const float*)d_in[6];
    float* out = (float*)d_out;

    char* p = (char*)d_ws;
    int4*  hh0     = (int4*)p;  p += (size_t)N_NODES * DIM * 2;   // 10.24 MB fp16 table
    int4*  hh1     = (int4*)p;  p += (size_t)N_NODES * DIM * 2;   // 10.24 MB fp16 table
    float* hf32    = (float*)p; p += (size_t)N_NODES * DIM * 4;   // 20.48 MB final f32
    float* inv0    = (float*)p; p += (size_t)N_NODES * 4;
    float* inv1    = (float*)p; p += (size_t)N_NODES * 4;
    // --- contiguous zero-init region ---
    int*   counts  = (int*)p;   p += (size_t)N_NODES * 4;
    int*   cursor  = (int*)p;   p += (size_t)N_NODES * 4;
    float* hgsum   = (float*)p; p += (size_t)N_GRAPHS * DIM * 4;
    int*   gcount  = (int*)p;   p += (size_t)N_GRAPHS * 4;
    // -----------------------------------
    int*   offsets = (int*)p;   p += (size_t)(N_NODES + 4) * 4;   // N+1 used, padded
    int*   csr_src = (int*)p;   p += (size_t)N_EDGES * 4;

    const int ZERO_N = 2 * N_NODES + N_GRAPHS * DIM + N_GRAPHS;

    // ---- CSR build (src/dst constant across layers) ----
    k_zero_int<<<(ZERO_N + 255) / 256, 256, 0, stream>>>(counts, ZERO_N);
    k_count<<<(N_EDGES + 255) / 256, 256, 0, stream>>>(dst, counts);
    k_scan<<<1, SCAN_T, 0, stream>>>(counts, offsets);
    k_scatter<<<(N_EDGES + 255) / 256, 256, 0, stream>>>(src, dst, offsets, cursor, csr_src);

    // ---- 3 AGNN layers on the fp16 table ----
    k_norm<<<N_NODES / 4, 256, 0, stream>>>(h_in, inv0, (__half2*)hh0);
    k_fused<false><<<N_NODES / 4, 256, 0, stream>>>(hh0, inv0, csr_src, offsets, betas, 0,
                                                    hh1, nullptr, inv1);
    k_fused<false><<<N_NODES / 4, 256, 0, stream>>>(hh1, inv1, csr_src, offsets, betas, 1,
                                                    hh0, nullptr, inv0);
    k_fused<true><<<N_NODES / 4, 256, 0, stream>>>(hh0, inv0, csr_src, offsets, betas, 2,
                                                   nullptr, hf32, inv1);

    // ---- readout ----
    k_pool_partial<<<POOL_BLOCKS, DIM, 0, stream>>>(hf32, gid, hgsum, gcount);
    k_cls<<<N_GRAPHS, DIM, 0, stream>>>(hgsum, gcount, W, bcls, out);
}

// Round 8
// 200.631 us; speedup vs baseline: 1.2781x; 1.0633x over previous
//
#include <hip/hip_runtime.h>
#include <hip/hip_fp16.h>
#include <math.h>

#define N_NODES 40000
#define N_EDGES 640000
#define DIM     128
#define N_GRAPHS 64
#define N_CLS   100
#define N_LAYERS 3
#define EPSN    1e-12f

// ---------------- CSR build ----------------

__global__ void k_zero_int(int* __restrict__ a, int n) {
    int i = blockIdx.x * blockDim.x + threadIdx.x;
    if (i < n) a[i] = 0;
}

// counts AND intra-node position (so scatter needs no atomics)
__global__ void k_count(const int* __restrict__ dst, int* __restrict__ counts,
                        int* __restrict__ posw) {
    int e = blockIdx.x * blockDim.x + threadIdx.x;
    if (e < N_EDGES) posw[e] = atomicAdd(&counts[dst[e]], 1);
}

#define SCAN_T 1024
#define SCAN_V 40   // SCAN_T * SCAN_V >= N_NODES ; N_NODES/SCAN_V = 1000 exact
__global__ void k_scan(const int* __restrict__ counts, int* __restrict__ offsets) {
    __shared__ int lds[SCAN_T];
    int t = threadIdx.x;
    int base = t * SCAN_V;
    int tsum = 0;
    if (base < N_NODES) {
        for (int k = 0; k < SCAN_V; ++k) tsum += counts[base + k];
    }
    lds[t] = tsum; __syncthreads();
    int x = tsum;
    for (int off = 1; off < SCAN_T; off <<= 1) {
        int y = (t >= off) ? lds[t - off] : 0;
        __syncthreads();
        x += y;
        lds[t] = x;
        __syncthreads();
    }
    int excl = x - tsum;
    if (base < N_NODES) {
        int run = excl;
        for (int k = 0; k < SCAN_V; ++k) {
            offsets[base + k] = run;
            run += counts[base + k];
        }
    }
    if (t == (N_NODES / SCAN_V)) offsets[N_NODES] = excl;  // total = E
}

__global__ void k_scatter(const int* __restrict__ src, const int* __restrict__ dst,
                          const int* __restrict__ offsets, const int* __restrict__ posw,
                          int* __restrict__ csr_src) {
    int e = blockIdx.x * blockDim.x + threadIdx.x;
    if (e >= N_EDGES) return;
    csr_src[offsets[dst[e]] + posw[e]] = src[e];
}

// ---------------- per-layer kernels ----------------

// one wave per node: inv[v] = 1/(||h_v||+eps) AND pack the f32 input row into
// the fp16 gather table. Lane l owns elements [2l, 2l+1].
__global__ void k_norm(const float* __restrict__ h, float* __restrict__ inv,
                       __half2* __restrict__ hh) {
    int node = (blockIdx.x * blockDim.x + threadIdx.x) >> 6;
    int lane = threadIdx.x & 63;
    if (node >= N_NODES) return;
    const float2* r2 = (const float2*)(h + (size_t)node * DIM);
    float2 v = r2[lane];
    float ss = v.x * v.x + v.y * v.y;
    #pragma unroll
    for (int o = 32; o; o >>= 1) ss += __shfl_xor(ss, o);
    if (lane == 0) inv[node] = 1.0f / (sqrtf(ss) + EPSN);
    hh[(size_t)node * 64 + lane] = __floats2half2_rn(v.x, v.y);
}

// Fused edge-score + segment-softmax + aggregate on the fp16 table.
// One wave per node; 4 groups of 16 lanes; each group owns 2 edges per batch
// of 8. Lane t owns features [8t..8t+7] = one int4 (8 halves) per row.
// All math in f32 (fp16 is storage only). Scores = beta*cosine in [-1,1], so
// exp is bounded: no max-subtraction needed (softmax shift-invariance).
// LAST layer: per-block LDS pool reduction + atomicAdd into hgsum (AvgPool
// fused; gids are sorted so ~99% of blocks are single-graph).
union H8 { int4 i4; __half2 h2[4]; };

__device__ __forceinline__ void cvt8(const H8& u, float* f) {
    #pragma unroll
    for (int k = 0; k < 4; ++k) {
        float2 v = __half22float2(u.h2[k]);
        f[2 * k]     = v.x;
        f[2 * k + 1] = v.y;
    }
}

template <bool LAST>
__global__ void k_fused(const int4* __restrict__ hh_in,      // fp16 table, 16 int4/row
                        const float* __restrict__ inv_in,
                        const int* __restrict__ csr_src,
                        const int* __restrict__ offsets,
                        const float* __restrict__ betas, int layer,
                        int4* __restrict__ hh_out,            // fp16 table (if !LAST)
                        float* __restrict__ inv_out,
                        const int* __restrict__ gid,          // (if LAST)
                        float* __restrict__ hgsum) {          // (if LAST)
    int node = (blockIdx.x * blockDim.x + threadIdx.x) >> 6;  // grid covers exactly N_NODES
    int lane = threadIdx.x & 63;
    int grp = lane >> 4;   // 0..3
    int t   = lane & 15;   // feature sublane: owns features [8t..8t+7]

    int off = offsets[node];
    int deg = offsets[node + 1] - off;

    size_t nrow16 = (size_t)node * 16;
    H8 selfu; selfu.i4 = hh_in[nrow16 + t];
    float hd[8]; cvt8(selfu, hd);
    float bi = betas[layer] * inv_in[node];

    float dsum = 0.f;
    float ac[8];
    #pragma unroll
    for (int k = 0; k < 8; ++k) ac[k] = 0.f;

    if (deg > 0) {
        int last = deg - 1;
        int jb = 0;
        // full batches: 8 edges (2 per group), no bounds checks
        for (; jb + 8 <= deg; jb += 8) {
            int s0 = csr_src[off + jb + grp];
            int s1 = csr_src[off + jb + 4 + grp];
            H8 u0, u1;
            u0.i4 = hh_in[(size_t)s0 * 16 + t];
            u1.i4 = hh_in[(size_t)s1 * 16 + t];
            float iv0 = inv_in[s0], iv1 = inv_in[s1];
            float f0[8], f1[8];
            cvt8(u0, f0); cvt8(u1, f1);
            float p0 = 0.f, p1 = 0.f;
            #pragma unroll
            for (int k = 0; k < 8; ++k) { p0 += f0[k] * hd[k]; p1 += f1[k] * hd[k]; }
            #pragma unroll
            for (int o = 8; o; o >>= 1) {
                p0 += __shfl_xor(p0, o);
                p1 += __shfl_xor(p1, o);
            }
            float w0 = __expf(bi * iv0 * p0);
            float w1 = __expf(bi * iv1 * p1);
            dsum += w0 + w1;
            #pragma unroll
            for (int k = 0; k < 8; ++k) ac[k] += w0 * f0[k] + w1 * f1[k];
        }
        // clamped tail: passes of 4 edges (1 per group), invalid -> w=0
        for (; jb < deg; jb += 4) {
            int j = jb + grp;
            bool valid = j <= last;
            int idx = valid ? j : last;
            int s = csr_src[off + idx];
            H8 u; u.i4 = hh_in[(size_t)s * 16 + t];
            float iv = inv_in[s];
            float f[8]; cvt8(u, f);
            float p = 0.f;
            #pragma unroll
            for (int k = 0; k < 8; ++k) p += f[k] * hd[k];
            #pragma unroll
            for (int o = 8; o; o >>= 1) p += __shfl_xor(p, o);
            float w = valid ? __expf(bi * iv * p) : 0.f;
            dsum += w;
            #pragma unroll
            for (int k = 0; k < 8; ++k) ac[k] += w * f[k];
        }

        // merge the 4 group partials (plain sums)
        #pragma unroll
        for (int o = 16; o < 64; o <<= 1) {
            dsum += __shfl_xor(dsum, o);
            #pragma unroll
            for (int k = 0; k < 8; ++k) ac[k] += __shfl_xor(ac[k], o);
        }
        float invd = 1.0f / dsum;
        #pragma unroll
        for (int k = 0; k < 8; ++k) ac[k] *= invd;
    }

    if (LAST) {
        // fused AvgPooling numerator: block = 4 nodes (sorted gid)
        __shared__ float spool[DIM];
        __shared__ int sg[4];
        int tid = threadIdx.x;
        int g = gid[node];
        if (lane == 0) sg[tid >> 6] = g;
        if (tid < DIM) spool[tid] = 0.f;
        __syncthreads();
        bool uni = (sg[0] == sg[1]) && (sg[1] == sg[2]) && (sg[2] == sg[3]);
        if (uni) {
            if (grp == 0) {
                #pragma unroll
                for (int k = 0; k < 8; ++k) atomicAdd(&spool[8 * t + k], ac[k]);
            }
            __syncthreads();
            if (tid < DIM) atomicAdd(&hgsum[(size_t)sg[0] * DIM + tid], spool[tid]);
        } else {
            if (grp == 0) {
                #pragma unroll
                for (int k = 0; k < 8; ++k)
                    atomicAdd(&hgsum[(size_t)g * DIM + 8 * t + k], ac[k]);
            }
        }
    } else {
        if (grp == 0) {
            H8 w;
            #pragma unroll
            for (int k = 0; k < 4; ++k)
                w.h2[k] = __floats2half2_rn(ac[2 * k], ac[2 * k + 1]);
            hh_out[nrow16 + t] = w.i4;
        }
        // fused inv-norm of the output row (for next layer's scores)
        float ss = 0.f;
        #pragma unroll
        for (int k = 0; k < 8; ++k) ss += ac[k] * ac[k];
        #pragma unroll
        for (int o = 8; o; o >>= 1) ss += __shfl_xor(ss, o);
        if (lane == 0) inv_out[node] = 1.0f / (sqrtf(ss) + EPSN);
    }
}

// ---------------- readout ----------------

// one block (128 threads) per graph; counts via binary search on sorted gid
__global__ void k_cls(const float* __restrict__ hgsum, const int* __restrict__ gid,
                      const float* __restrict__ W, const float* __restrict__ b,
                      float* __restrict__ out) {
    int g = blockIdx.x;
    int c = threadIdx.x;
    __shared__ float invc_s;
    if (c == 0) {
        int lo = 0, hi = N_NODES;
        while (lo < hi) { int mid = (lo + hi) >> 1; if (gid[mid] < g) lo = mid + 1; else hi = mid; }
        int start = lo;
        lo = 0; hi = N_NODES;
        while (lo < hi) { int mid = (lo + hi) >> 1; if (gid[mid] < g + 1) lo = mid + 1; else hi = mid; }
        invc_s = 1.0f / fmaxf((float)(lo - start), 1.0f);
    }
    __syncthreads();
    if (c >= N_CLS) return;
    float acc = 0.f;
    #pragma unroll 8
    for (int d = 0; d < DIM; ++d) acc += hgsum[g * DIM + d] * W[d * N_CLS + c];
    out[g * N_CLS + c] = b[c] + acc * invc_s;
}

// ---------------- launch ----------------

extern "C" void kernel_launch(void* const* d_in, const int* in_sizes, int n_in,
                              void* d_out, int out_size, void* d_ws, size_t ws_size,
                              hipStream_t stream) {
    const float* h_in  = (const float*)d_in[0];
    const int*   src   = (const int*)  d_in[1];
    const int*   dst   = (const int*)  d_in[2];
    const int*   gid   = (const int*)  d_in[3];
    const float* betas = (const float*)d_in[4];
    const float* W     = (const float*)d_in[5];
    const float* bcls  = (const float*)d_in[6];
    float* out = (float*)d_out;

    char* p = (char*)d_ws;
    int4*  hh0     = (int4*)p;  p += (size_t)N_NODES * DIM * 2;   // 10.24 MB fp16 table
    int4*  hh1     = (int4*)p;  p += (size_t)N_NODES * DIM * 2;   // 10.24 MB fp16 table
    float* inv0    = (float*)p; p += (size_t)N_NODES * 4;
    float* inv1    = (float*)p; p += (size_t)N_NODES * 4;
    // --- contiguous zero-init region ---
    int*   counts  = (int*)p;   p += (size_t)N_NODES * 4;
    float* hgsum   = (float*)p; p += (size_t)N_GRAPHS * DIM * 4;
    // -----------------------------------
    int*   offsets = (int*)p;   p += (size_t)(N_NODES + 4) * 4;   // N+1 used, padded
    int*   posw    = (int*)p;   p += (size_t)N_EDGES * 4;
    int*   csr_src = (int*)p;   p += (size_t)N_EDGES * 4;

    const int ZERO_N = N_NODES + N_GRAPHS * DIM;

    // ---- CSR build (src/dst constant across layers) ----
    k_zero_int<<<(ZERO_N + 255) / 256, 256, 0, stream>>>(counts, ZERO_N);
    k_count<<<(N_EDGES + 255) / 256, 256, 0, stream>>>(dst, counts, posw);
    k_scan<<<1, SCAN_T, 0, stream>>>(counts, offsets);
    k_scatter<<<(N_EDGES + 255) / 256, 256, 0, stream>>>(src, dst, offsets, posw, csr_src);

    // ---- 3 AGNN layers on the fp16 table ----
    k_norm<<<N_NODES / 4, 256, 0, stream>>>(h_in, inv0, (__half2*)hh0);
    k_fused<false><<<N_NODES / 4, 256, 0, stream>>>(hh0, inv0, csr_src, offsets, betas, 0,
                                                    hh1, inv1, nullptr, nullptr);
    k_fused<false><<<N_NODES / 4, 256, 0, stream>>>(hh1, inv1, csr_src, offsets, betas, 1,
                                                    hh0, inv0, nullptr, nullptr);
    k_fused<true><<<N_NODES / 4, 256, 0, stream>>>(hh0, inv0, csr_src, offsets, betas, 2,
                                                   nullptr, nullptr, gid, hgsum);

    // ---- readout ----
    k_cls<<<N_GRAPHS, DIM, 0, stream>>>(hgsum, gid, W, bcls, out);
}